// Round 3
// baseline (68.291 us; speedup 1.0000x reference)
//
#include <hip/hip_runtime.h>
#include <math.h>

// B=4, X=128, T=256, HIDDEN=128, EMB=128, DH=32, LATENT=32, K=1024
// Outputs concat: u (131072), zt (1048576), px (524288)
//
// u[b,t,x] = K0 + sum_k zt[b,t,k] * px[b,x,k] * wcd[k>>5]   (wcd pre-scaled by 1/32)
//
// ws layout (floats):
//   [0..511]    gx[b][j] = (ex @ px_We + px_be)
//   [512..1023] gt[b][j] = (et @ zt_We + zt_be)
//   [1024..1055] wcd[d] * (1/32)
//   [1056]      K0

__global__ __launch_bounds__(128) void prep_kernel(
    const float* __restrict__ param,
    const float* __restrict__ p2e_W1, const float* __restrict__ p2e_b1,
    const float* __restrict__ p2e_W2, const float* __restrict__ p2e_b2,
    const float* __restrict__ e2ex_W, const float* __restrict__ e2ex_b,
    const float* __restrict__ e2et_W, const float* __restrict__ e2et_b,
    const float* __restrict__ px_We,  const float* __restrict__ px_be,
    const float* __restrict__ zt_We,  const float* __restrict__ zt_be,
    const float* __restrict__ h0,
    const float* __restrict__ blk_W1, const float* __restrict__ blk_b1,
    const float* __restrict__ blk_Wc, const float* __restrict__ blk_bc,
    const float* __restrict__ blk_W2, const float* __restrict__ blk_b2,
    const float* __restrict__ d_W,    const float* __restrict__ d_b,
    float* __restrict__ ws)
{
    const int j = threadIdx.x;           // 0..127
    __shared__ float sh0[128], sh1[128], sh2[128];

    if (blockIdx.x < 4) {
        const int b = blockIdx.x;
        float acc = p2e_b1[j];
        #pragma unroll
        for (int p = 0; p < 16; ++p) acc += param[b * 16 + p] * p2e_W1[p * 128 + j];
        sh0[j] = sinf(acc);
        __syncthreads();
        float e = p2e_b2[j];
        for (int k = 0; k < 128; ++k) e += sh0[k] * p2e_W2[k * 128 + j];
        sh1[j] = e;
        __syncthreads();
        float ax = e2ex_b[j], at = e2et_b[j];
        for (int k = 0; k < 128; ++k) {
            float ek = sh1[k];
            ax += ek * e2ex_W[k * 128 + j];
            at += ek * e2et_W[k * 128 + j];
        }
        sh0[j] = ax; sh2[j] = at;
        __syncthreads();
        float gx = px_be[j], gt = zt_be[j];
        for (int k = 0; k < 128; ++k) {
            gx += sh0[k] * px_We[k * 128 + j];
            gt += sh2[k] * zt_We[k * 128 + j];
        }
        ws[b * 128 + j]       = gx;
        ws[512 + b * 128 + j] = gt;
    } else {
        float sacc = blk_b1[j];
        for (int k = 0; k < 128; ++k) sacc += h0[k] * blk_W1[k * 128 + j];
        float s = sinf(sacc);
        float w2d = 0.f;
        for (int m = 0; m < 128; ++m) w2d += blk_W2[j * 128 + m] * d_W[m];
        float sw = s * w2d;
        sh0[j] = sw;
        sh1[j] = (h0[j] + blk_b2[j]) * d_W[j] + sw * blk_bc[j];
        __syncthreads();
        if (j < 32) {
            float w = 0.f;
            for (int k = 0; k < 128; ++k) w += blk_Wc[j * 128 + k] * sh0[k];
            ws[1024 + j] = w * (1.0f / 32.0f);
        }
        for (int off = 64; off > 0; off >>= 1) {
            if (j < off) sh1[j] += sh1[j + off];
            __syncthreads();
        }
        if (j == 0) ws[1056] = sh1[0] + d_b[0];
    }
}

// feat: 384 blocks x 256 thr. blk<128: px rows r0=blk*4; else zt rows r0=(blk-128)*4.
// Thread owns one float4 col (c0=tid*4) for 4 rows; batched 8-k loads for ILP.
__global__ __launch_bounds__(256) void feat_kernel(
    const float* __restrict__ x, const float* __restrict__ t,
    const float* __restrict__ px_Wx, const float* __restrict__ px_bx,
    const float* __restrict__ px_Wo, const float* __restrict__ px_bo,
    const float* __restrict__ px_mult,
    const float* __restrict__ zt_Wx, const float* __restrict__ zt_bx,
    const float* __restrict__ zt_Wo, const float* __restrict__ zt_bo,
    const float* __restrict__ zt_mult,
    const float* __restrict__ ws,
    float* __restrict__ out_px, float* __restrict__ out_zt)
{
    const int tid = threadIdx.x;
    const bool is_zt = (blockIdx.x >= 128);
    const int r0 = (is_zt ? (int)blockIdx.x - 128 : (int)blockIdx.x) * 4;
    const int b  = is_zt ? (r0 >> 8) : (r0 >> 7);

    const float* Wx = is_zt ? zt_Wx : px_Wx;
    const float* bx = is_zt ? zt_bx : px_bx;
    const float* Wo = is_zt ? zt_Wo : px_Wo;
    const float* bo = is_zt ? zt_bo : px_bo;
    const float* coord = is_zt ? t : x;
    const float  mult  = is_zt ? zt_mult[0] : px_mult[0];
    const float* g = ws + (is_zt ? 512 : 0) + b * 128;
    float* outp = is_zt ? out_zt : out_px;

    __shared__ float f[4][128];
    {
        const int j = tid & 127;
        const int rr0 = (tid >> 7) * 2;
        const float gv = g[j];
        const float wxj = Wx[j], bxj = bx[j];
        f[rr0][j]     = sinf(coord[r0 + rr0]     * wxj + bxj) * gv;
        f[rr0 + 1][j] = sinf(coord[r0 + rr0 + 1] * wxj + bxj) * gv;
    }
    __syncthreads();

    const int c0 = tid * 4;
    const float4 bias = *(const float4*)&bo[c0];
    float4 acc[4] = {bias, bias, bias, bias};

    for (int k0 = 0; k0 < 128; k0 += 8) {
        float4 w[8];
        #pragma unroll
        for (int i = 0; i < 8; ++i)
            w[i] = *(const float4*)&Wo[(k0 + i) * 1024 + c0];
        #pragma unroll
        for (int i = 0; i < 8; ++i) {
            #pragma unroll
            for (int rr = 0; rr < 4; ++rr) {
                const float fv = f[rr][k0 + i];
                acc[rr].x += fv * w[i].x;
                acc[rr].y += fv * w[i].y;
                acc[rr].z += fv * w[i].z;
                acc[rr].w += fv * w[i].w;
            }
        }
    }
    #pragma unroll
    for (int rr = 0; rr < 4; ++rr) {
        float4 v;
        v.x = mult * acc[rr].x; v.y = mult * acc[rr].y;
        v.z = mult * acc[rr].z; v.w = mult * acc[rr].w;
        *(float4*)&outp[(r0 + rr) * 1024 + c0] = v;
    }
}

// u: 256 blocks = 4b x 32 t-tiles(8 rows) x 2 x-halves(64). 256 thr.
// Thread (tx=tid&31, ty=tid>>5): outputs (t0+ty, x0+tx) and (t0+ty, x0+tx+32).
// K chunked at 128 with register double-buffer prefetch.
__global__ __launch_bounds__(256) void u_kernel(
    const float* __restrict__ zt, const float* __restrict__ px,
    const float* __restrict__ ws, float* __restrict__ out_u)
{
    const int tid = threadIdx.x;
    const int blk = blockIdx.x;
    const int b   = blk >> 6;
    const int rem = blk & 63;
    const int t0  = (rem >> 1) * 8;
    const int x0  = (rem & 1) * 64;

    __shared__ float wc[32];
    __shared__ float zts[8][132];    // stride 528B, f4-aligned
    __shared__ float pxs[64][132];

    if (tid < 32) wc[tid] = ws[1024 + tid];
    const float K0 = ws[1056];

    const int tx = tid & 31;
    const int ty = tid >> 5;

    const float* ztb = zt + (b * 256 + t0) * 1024;
    const float* pxb = px + (b * 128 + x0) * 1024;

    const int zkk = (tid & 31) * 4;      // zt fill: row=ty, k=zkk
    float4 zf = *(const float4*)&ztb[ty * 1024 + zkk];
    float4 pf[8];
    #pragma unroll
    for (int i = 0; i < 8; ++i) {
        const int m = tid + 256 * i;
        pf[i] = *(const float4*)&pxb[(m >> 5) * 1024 + (m & 31) * 4];
    }
    __syncthreads();                     // wc visible

    float acc0 = 0.f, acc1 = 0.f;
    for (int kc = 0; kc < 1024; kc += 128) {
        {
            const float s = wc[(kc + zkk) >> 5];
            float4 v = zf;
            v.x *= s; v.y *= s; v.z *= s; v.w *= s;
            *(float4*)&zts[ty][zkk] = v;
            #pragma unroll
            for (int i = 0; i < 8; ++i) {
                const int m = tid + 256 * i;
                *(float4*)&pxs[m >> 5][(m & 31) * 4] = pf[i];
            }
        }
        __syncthreads();
        if (kc + 128 < 1024) {           // prefetch next chunk (overlaps compute)
            zf = *(const float4*)&ztb[ty * 1024 + kc + 128 + zkk];
            #pragma unroll
            for (int i = 0; i < 8; ++i) {
                const int m = tid + 256 * i;
                pf[i] = *(const float4*)&pxb[(m >> 5) * 1024 + kc + 128 + (m & 31) * 4];
            }
        }
        #pragma unroll
        for (int kk = 0; kk < 128; kk += 4) {
            const float4 z  = *(const float4*)&zts[ty][kk];
            const float4 p0 = *(const float4*)&pxs[tx][kk];
            const float4 p1 = *(const float4*)&pxs[tx + 32][kk];
            acc0 += z.x * p0.x + z.y * p0.y + z.z * p0.z + z.w * p0.w;
            acc1 += z.x * p1.x + z.y * p1.y + z.z * p1.z + z.w * p1.w;
        }
        __syncthreads();
    }
    out_u[(b * 256 + t0 + ty) * 128 + x0 + tx]      = K0 + acc0;
    out_u[(b * 256 + t0 + ty) * 128 + x0 + tx + 32] = K0 + acc1;
}

extern "C" void kernel_launch(void* const* d_in, const int* in_sizes, int n_in,
                              void* d_out, int out_size, void* d_ws, size_t ws_size,
                              hipStream_t stream) {
    const float* x       = (const float*)d_in[0];
    const float* t       = (const float*)d_in[1];
    const float* param   = (const float*)d_in[2];
    const float* p2e_W1  = (const float*)d_in[3];
    const float* p2e_b1  = (const float*)d_in[4];
    const float* p2e_W2  = (const float*)d_in[5];
    const float* p2e_b2  = (const float*)d_in[6];
    const float* e2ex_W  = (const float*)d_in[7];
    const float* e2ex_b  = (const float*)d_in[8];
    const float* e2et_W  = (const float*)d_in[9];
    const float* e2et_b  = (const float*)d_in[10];
    const float* px_Wx   = (const float*)d_in[11];
    const float* px_bx   = (const float*)d_in[12];
    const float* px_We   = (const float*)d_in[13];
    const float* px_be   = (const float*)d_in[14];
    const float* px_Wo   = (const float*)d_in[15];
    const float* px_bo   = (const float*)d_in[16];
    const float* px_mult = (const float*)d_in[17];
    const float* zt_Wx   = (const float*)d_in[18];
    const float* zt_bx   = (const float*)d_in[19];
    const float* zt_We   = (const float*)d_in[20];
    const float* zt_be   = (const float*)d_in[21];
    const float* zt_Wo   = (const float*)d_in[22];
    const float* zt_bo   = (const float*)d_in[23];
    const float* zt_mult = (const float*)d_in[24];
    const float* h0      = (const float*)d_in[25];
    const float* blk_W1  = (const float*)d_in[26];
    const float* blk_b1  = (const float*)d_in[27];
    const float* blk_Wc  = (const float*)d_in[28];
    const float* blk_bc  = (const float*)d_in[29];
    const float* blk_W2  = (const float*)d_in[30];
    const float* blk_b2  = (const float*)d_in[31];
    const float* d_W     = (const float*)d_in[32];
    const float* d_bias  = (const float*)d_in[33];

    float* out    = (float*)d_out;
    float* out_u  = out;                       // 131072
    float* out_zt = out + 131072;              // 1048576
    float* out_px = out + 131072 + 1048576;    // 524288

    float* ws = (float*)d_ws;

    prep_kernel<<<5, 128, 0, stream>>>(
        param, p2e_W1, p2e_b1, p2e_W2, p2e_b2,
        e2ex_W, e2ex_b, e2et_W, e2et_b,
        px_We, px_be, zt_We, zt_be,
        h0, blk_W1, blk_b1, blk_Wc, blk_bc, blk_W2, blk_b2,
        d_W, d_bias, ws);

    feat_kernel<<<384, 256, 0, stream>>>(
        x, t,
        px_Wx, px_bx, px_Wo, px_bo, px_mult,
        zt_Wx, zt_bx, zt_Wo, zt_bo, zt_mult,
        ws, out_px, out_zt);

    u_kernel<<<256, 256, 0, stream>>>(out_zt, out_px, ws, out_u);
}

// Round 4
// 59.589 us; speedup vs baseline: 1.1460x; 1.1460x over previous
//
#include <hip/hip_runtime.h>
#include <math.h>

// B=4, X=128, T=256, HIDDEN=128, EMB=128, DH=32, LATENT=32, K=1024
// Outputs concat: u (131072), zt (1048576), px (524288)
//
// u[b,t,x] = K0 + sum_k zt[b,t,k] * px[b,x,k] * wc[k>>5]   (wc = wcd/32)
//
// ws layout (floats):
//   [0..511]     gx[b][j] = ex @ px_We + px_be
//   [512..1023]  gt[b][j] = et @ zt_We + zt_be
//   [1024..1055] wc[d] = wcd[d]/32
//   [1056]       K0

__global__ __launch_bounds__(128) void prep_kernel(
    const float* __restrict__ param,
    const float* __restrict__ p2e_W1, const float* __restrict__ p2e_b1,
    const float* __restrict__ p2e_W2, const float* __restrict__ p2e_b2,
    const float* __restrict__ e2ex_W, const float* __restrict__ e2ex_b,
    const float* __restrict__ e2et_W, const float* __restrict__ e2et_b,
    const float* __restrict__ px_We,  const float* __restrict__ px_be,
    const float* __restrict__ zt_We,  const float* __restrict__ zt_be,
    const float* __restrict__ h0,
    const float* __restrict__ blk_W1, const float* __restrict__ blk_b1,
    const float* __restrict__ blk_Wc, const float* __restrict__ blk_bc,
    const float* __restrict__ blk_W2, const float* __restrict__ blk_b2,
    const float* __restrict__ d_W,    const float* __restrict__ d_b,
    float* __restrict__ ws)
{
    const int j = threadIdx.x;           // 0..127
    __shared__ float sh0[128], sh1[128], sh2[128];

    if (blockIdx.x < 4) {
        const int b = blockIdx.x;
        float acc = p2e_b1[j];
        #pragma unroll
        for (int p = 0; p < 16; ++p) acc += param[b * 16 + p] * p2e_W1[p * 128 + j];
        sh0[j] = __sinf(acc);
        __syncthreads();
        float e = p2e_b2[j];
        #pragma unroll 8
        for (int k = 0; k < 128; ++k) e += sh0[k] * p2e_W2[k * 128 + j];
        sh1[j] = e;
        __syncthreads();
        float ax = e2ex_b[j], at = e2et_b[j];
        #pragma unroll 8
        for (int k = 0; k < 128; ++k) {
            float ek = sh1[k];
            ax += ek * e2ex_W[k * 128 + j];
            at += ek * e2et_W[k * 128 + j];
        }
        sh0[j] = ax; sh2[j] = at;
        __syncthreads();
        float gx = px_be[j], gt = zt_be[j];
        #pragma unroll 8
        for (int k = 0; k < 128; ++k) {
            gx += sh0[k] * px_We[k * 128 + j];
            gt += sh2[k] * zt_We[k * 128 + j];
        }
        ws[b * 128 + j]       = gx;
        ws[512 + b * 128 + j] = gt;
    } else {
        float sacc = blk_b1[j];
        #pragma unroll 8
        for (int k = 0; k < 128; ++k) sacc += h0[k] * blk_W1[k * 128 + j];
        float s = __sinf(sacc);
        float w2d = 0.f;
        #pragma unroll 8
        for (int m = 0; m < 128; ++m) w2d += blk_W2[j * 128 + m] * d_W[m];
        float sw = s * w2d;
        sh0[j] = sw;
        sh1[j] = (h0[j] + blk_b2[j]) * d_W[j] + sw * blk_bc[j];
        __syncthreads();
        if (j < 32) {
            float w = 0.f;
            #pragma unroll 8
            for (int k = 0; k < 128; ++k) w += blk_Wc[j * 128 + k] * sh0[k];
            ws[1024 + j] = w * (1.0f / 32.0f);
        }
        for (int off = 64; off > 0; off >>= 1) {
            if (j < off) sh1[j] += sh1[j + off];
            __syncthreads();
        }
        if (j == 0) ws[1056] = sh1[0] + d_b[0];
    }
}

// feat: 384 blocks x 128 thr. blk<128: px (rt=blk>>1, cs=blk&1), else zt.
// Block: 8 rows x 512 cols (col half cs). Thread: 1 float4 col-group, acc[8].
__global__ __launch_bounds__(128) void feat_kernel(
    const float* __restrict__ x, const float* __restrict__ t,
    const float* __restrict__ px_Wx, const float* __restrict__ px_bx,
    const float* __restrict__ px_Wo, const float* __restrict__ px_bo,
    const float* __restrict__ px_mult,
    const float* __restrict__ zt_Wx, const float* __restrict__ zt_bx,
    const float* __restrict__ zt_Wo, const float* __restrict__ zt_bo,
    const float* __restrict__ zt_mult,
    const float* __restrict__ ws,
    float* __restrict__ out_px, float* __restrict__ out_zt)
{
    const int tid = threadIdx.x;        // 0..127
    const bool is_zt = (blockIdx.x >= 128);
    const int idx = is_zt ? ((int)blockIdx.x - 128) : (int)blockIdx.x;
    const int rt = idx >> 1;
    const int cs = idx & 1;
    const int r0 = rt * 8;
    const int b  = is_zt ? (r0 >> 8) : (r0 >> 7);

    const float* Wx = is_zt ? zt_Wx : px_Wx;
    const float* bx = is_zt ? zt_bx : px_bx;
    const float* Wo = is_zt ? zt_Wo : px_Wo;
    const float* bo = is_zt ? zt_bo : px_bo;
    const float* coord = is_zt ? t : x;
    const float  mult  = is_zt ? zt_mult[0] : px_mult[0];
    const float* g = ws + (is_zt ? 512 : 0) + b * 128;
    float* outp = is_zt ? out_zt : out_px;

    __shared__ float f[8][128];
    {
        const float gv = g[tid];
        const float wxj = Wx[tid], bxj = bx[tid];
        #pragma unroll
        for (int rr = 0; rr < 8; ++rr)
            f[rr][tid] = __sinf(coord[r0 + rr] * wxj + bxj) * gv;
    }
    __syncthreads();

    const int c0 = cs * 512 + tid * 4;
    const float4 bias = *(const float4*)&bo[c0];
    float4 acc[8];
    #pragma unroll
    for (int rr = 0; rr < 8; ++rr) acc[rr] = bias;

    for (int k0 = 0; k0 < 128; k0 += 8) {
        float4 w[8];
        #pragma unroll
        for (int i = 0; i < 8; ++i)
            w[i] = *(const float4*)&Wo[(k0 + i) * 1024 + c0];
        #pragma unroll
        for (int i = 0; i < 8; ++i) {
            #pragma unroll
            for (int rr = 0; rr < 8; ++rr) {
                const float fv = f[rr][k0 + i];
                acc[rr].x += fv * w[i].x;
                acc[rr].y += fv * w[i].y;
                acc[rr].z += fv * w[i].z;
                acc[rr].w += fv * w[i].w;
            }
        }
    }
    #pragma unroll
    for (int rr = 0; rr < 8; ++rr) {
        float4 v;
        v.x = mult * acc[rr].x; v.y = mult * acc[rr].y;
        v.z = mult * acc[rr].z; v.w = mult * acc[rr].w;
        *(float4*)&outp[(r0 + rr) * 1024 + c0] = v;
    }
}

// u: 256 blocks = 4b x 16 t-tiles(16 rows) x 4 x-quarters(32). 256 thr.
// Thread (tx=tid&31, ty=tid>>5): outputs (t0+ty, x0+tx), (t0+ty+8, x0+tx).
// px chunk staged in LDS (pre-scaled by wc); zt rows read from global into
// registers (lane-duplicated -> single transaction), 16 loads in flight.
// Inner loop: 1 ds_read_b128 + 8 FMA per 4-k.
__global__ __launch_bounds__(256) void u_kernel(
    const float* __restrict__ zt, const float* __restrict__ px,
    const float* __restrict__ ws, float* __restrict__ out_u)
{
    const int tid = threadIdx.x;
    const int blk = blockIdx.x;
    const int b   = blk >> 6;
    const int rem = blk & 63;
    const int t0  = (rem >> 2) * 16;
    const int x0  = (rem & 3) * 32;

    __shared__ float4 pxs4[32][65];   // 32 rows x 64 f4, +1 f4 pad
    __shared__ float wcs[32];

    if (tid < 32) wcs[tid] = ws[1024 + tid];
    const float K0 = ws[1056];

    const int tx = tid & 31;
    const int ty = tid >> 5;          // 0..7

    const float* ztb = zt + (b * 256 + t0) * 1024;
    const float* pxb = px + (b * 128 + x0) * 1024;

    __syncthreads();                  // wcs visible

    float acc0 = 0.f, acc1 = 0.f;

    for (int chunk = 0; chunk < 4; ++chunk) {
        const int kc = chunk * 256;
        if (chunk) __syncthreads();   // previous reads done before overwrite
        // stage px chunk: 32 rows x 64 f4, scaled by wc
        #pragma unroll
        for (int i = 0; i < 8; ++i) {
            const int m  = tid + 256 * i;
            const int xx = m >> 6;            // 0..31
            const int jf = m & 63;            // f4 within chunk
            float4 v = *(const float4*)&pxb[xx * 1024 + kc + jf * 4];
            const float s = wcs[(kc >> 5) + (jf >> 3)];
            v.x *= s; v.y *= s; v.z *= s; v.w *= s;
            pxs4[xx][jf] = v;
        }
        __syncthreads();

        for (int jj = 0; jj < 8; ++jj) {
            float4 za[8], zb[8];
            const int koff = kc + jj * 32;
            #pragma unroll
            for (int j2 = 0; j2 < 8; ++j2) {
                za[j2] = *(const float4*)&ztb[ty * 1024 + koff + j2 * 4];
                zb[j2] = *(const float4*)&ztb[(ty + 8) * 1024 + koff + j2 * 4];
            }
            #pragma unroll
            for (int j2 = 0; j2 < 8; ++j2) {
                const float4 p = pxs4[tx][jj * 8 + j2];
                acc0 += za[j2].x * p.x + za[j2].y * p.y
                      + za[j2].z * p.z + za[j2].w * p.w;
                acc1 += zb[j2].x * p.x + zb[j2].y * p.y
                      + zb[j2].z * p.z + zb[j2].w * p.w;
            }
        }
    }

    out_u[(b * 256 + t0 + ty)     * 128 + x0 + tx] = K0 + acc0;
    out_u[(b * 256 + t0 + ty + 8) * 128 + x0 + tx] = K0 + acc1;
}

extern "C" void kernel_launch(void* const* d_in, const int* in_sizes, int n_in,
                              void* d_out, int out_size, void* d_ws, size_t ws_size,
                              hipStream_t stream) {
    const float* x       = (const float*)d_in[0];
    const float* t       = (const float*)d_in[1];
    const float* param   = (const float*)d_in[2];
    const float* p2e_W1  = (const float*)d_in[3];
    const float* p2e_b1  = (const float*)d_in[4];
    const float* p2e_W2  = (const float*)d_in[5];
    const float* p2e_b2  = (const float*)d_in[6];
    const float* e2ex_W  = (const float*)d_in[7];
    const float* e2ex_b  = (const float*)d_in[8];
    const float* e2et_W  = (const float*)d_in[9];
    const float* e2et_b  = (const float*)d_in[10];
    const float* px_Wx   = (const float*)d_in[11];
    const float* px_bx   = (const float*)d_in[12];
    const float* px_We   = (const float*)d_in[13];
    const float* px_be   = (const float*)d_in[14];
    const float* px_Wo   = (const float*)d_in[15];
    const float* px_bo   = (const float*)d_in[16];
    const float* px_mult = (const float*)d_in[17];
    const float* zt_Wx   = (const float*)d_in[18];
    const float* zt_bx   = (const float*)d_in[19];
    const float* zt_We   = (const float*)d_in[20];
    const float* zt_be   = (const float*)d_in[21];
    const float* zt_Wo   = (const float*)d_in[22];
    const float* zt_bo   = (const float*)d_in[23];
    const float* zt_mult = (const float*)d_in[24];
    const float* h0      = (const float*)d_in[25];
    const float* blk_W1  = (const float*)d_in[26];
    const float* blk_b1  = (const float*)d_in[27];
    const float* blk_Wc  = (const float*)d_in[28];
    const float* blk_bc  = (const float*)d_in[29];
    const float* blk_W2  = (const float*)d_in[30];
    const float* blk_b2  = (const float*)d_in[31];
    const float* d_W     = (const float*)d_in[32];
    const float* d_bias  = (const float*)d_in[33];

    float* out    = (float*)d_out;
    float* out_u  = out;                       // 131072
    float* out_zt = out + 131072;              // 1048576
    float* out_px = out + 131072 + 1048576;    // 524288

    float* ws = (float*)d_ws;

    prep_kernel<<<5, 128, 0, stream>>>(
        param, p2e_W1, p2e_b1, p2e_W2, p2e_b2,
        e2ex_W, e2ex_b, e2et_W, e2et_b,
        px_We, px_be, zt_We, zt_be,
        h0, blk_W1, blk_b1, blk_Wc, blk_bc, blk_W2, blk_b2,
        d_W, d_bias, ws);

    feat_kernel<<<384, 128, 0, stream>>>(
        x, t,
        px_Wx, px_bx, px_Wo, px_bo, px_mult,
        zt_Wx, zt_bx, zt_Wo, zt_bo, zt_mult,
        ws, out_px, out_zt);

    u_kernel<<<256, 256, 0, stream>>>(out_zt, out_px, ws, out_u);
}

// Round 6
// 55.914 us; speedup vs baseline: 1.2214x; 1.0657x over previous
//
#include <hip/hip_runtime.h>
#include <math.h>

// B=4, X=128, T=256, HIDDEN=128, EMB=128, DH=32, LATENT=32, K=1024
// Outputs concat: u (131072), zt (1048576), px (524288)
//
// u[b,t,x] = K0 + sum_k zt[b,t,k] * px[b,x,k] * wc[k>>5]   (wc = wcd/32)
//
// ws layout (floats):
//   [0..511]     gx[b][j] = ex @ px_We + px_be
//   [512..1023]  gt[b][j] = et @ zt_We + zt_be
//   [1024..1055] wc[d] = wcd[d]/32
//   [1056]       K0

__global__ __launch_bounds__(128) void prep_kernel(
    const float* __restrict__ param,
    const float* __restrict__ p2e_W1, const float* __restrict__ p2e_b1,
    const float* __restrict__ p2e_W2, const float* __restrict__ p2e_b2,
    const float* __restrict__ e2ex_W, const float* __restrict__ e2ex_b,
    const float* __restrict__ e2et_W, const float* __restrict__ e2et_b,
    const float* __restrict__ px_We,  const float* __restrict__ px_be,
    const float* __restrict__ zt_We,  const float* __restrict__ zt_be,
    const float* __restrict__ h0,
    const float* __restrict__ blk_W1, const float* __restrict__ blk_b1,
    const float* __restrict__ blk_Wc, const float* __restrict__ blk_bc,
    const float* __restrict__ blk_W2, const float* __restrict__ blk_b2,
    const float* __restrict__ d_W,    const float* __restrict__ d_b,
    float* __restrict__ ws)
{
    const int j = threadIdx.x;           // 0..127
    __shared__ float sh0[128], sh1[128], sh2[128];

    if (blockIdx.x < 4) {
        const int b = blockIdx.x;
        float acc = p2e_b1[j];
        #pragma unroll
        for (int p = 0; p < 16; ++p) acc += param[b * 16 + p] * p2e_W1[p * 128 + j];
        sh0[j] = __sinf(acc);
        __syncthreads();
        float e = p2e_b2[j];
        #pragma unroll 8
        for (int k = 0; k < 128; ++k) e += sh0[k] * p2e_W2[k * 128 + j];
        sh1[j] = e;
        __syncthreads();
        float ax = e2ex_b[j], at = e2et_b[j];
        #pragma unroll 8
        for (int k = 0; k < 128; ++k) {
            float ek = sh1[k];
            ax += ek * e2ex_W[k * 128 + j];
            at += ek * e2et_W[k * 128 + j];
        }
        sh0[j] = ax; sh2[j] = at;
        __syncthreads();
        float gx = px_be[j], gt = zt_be[j];
        #pragma unroll 8
        for (int k = 0; k < 128; ++k) {
            gx += sh0[k] * px_We[k * 128 + j];
            gt += sh2[k] * zt_We[k * 128 + j];
        }
        ws[b * 128 + j]       = gx;
        ws[512 + b * 128 + j] = gt;
    } else {
        float sacc = blk_b1[j];
        #pragma unroll 8
        for (int k = 0; k < 128; ++k) sacc += h0[k] * blk_W1[k * 128 + j];
        float s = __sinf(sacc);
        float w2d = 0.f;
        #pragma unroll 8
        for (int m = 0; m < 128; ++m) w2d += blk_W2[j * 128 + m] * d_W[m];
        float sw = s * w2d;
        sh0[j] = sw;
        sh1[j] = (h0[j] + blk_b2[j]) * d_W[j] + sw * blk_bc[j];
        __syncthreads();
        if (j < 32) {
            float w = 0.f;
            #pragma unroll 8
            for (int k = 0; k < 128; ++k) w += blk_Wc[j * 128 + k] * sh0[k];
            ws[1024 + j] = w * (1.0f / 32.0f);
        }
        for (int off = 64; off > 0; off >>= 1) {
            if (j < off) sh1[j] += sh1[j + off];
            __syncthreads();
        }
        if (j == 0) ws[1056] = sh1[0] + d_b[0];
    }
}

__device__ __forceinline__ void fma4(float4& a, float s, const float4& v) {
    a.x += s * v.x; a.y += s * v.y; a.z += s * v.z; a.w += s * v.w;
}

// feat: 384 blocks x 128 thr. blk<128: px (rt=blk>>1, cs=blk&1), else zt.
// Block: 8 rows x 512 cols. Thread: one float4 col-group, acc[8].
// Register double-buffer wA/wB (8 deep each) keeps 8 global loads in flight
// while 256 FMAs consume the other buffer. launch_bounds(128,1) unlocks VGPRs.
__global__ __launch_bounds__(128, 1) void feat_kernel(
    const float* __restrict__ x, const float* __restrict__ t,
    const float* __restrict__ px_Wx, const float* __restrict__ px_bx,
    const float* __restrict__ px_Wo, const float* __restrict__ px_bo,
    const float* __restrict__ px_mult,
    const float* __restrict__ zt_Wx, const float* __restrict__ zt_bx,
    const float* __restrict__ zt_Wo, const float* __restrict__ zt_bo,
    const float* __restrict__ zt_mult,
    const float* __restrict__ ws,
    float* __restrict__ out_px, float* __restrict__ out_zt)
{
    const int tid = threadIdx.x;        // 0..127
    const bool is_zt = (blockIdx.x >= 128);
    const int idx = is_zt ? ((int)blockIdx.x - 128) : (int)blockIdx.x;
    const int rt = idx >> 1;
    const int cs = idx & 1;
    const int r0 = rt * 8;
    const int b  = is_zt ? (r0 >> 8) : (r0 >> 7);

    const float* Wx = is_zt ? zt_Wx : px_Wx;
    const float* bx = is_zt ? zt_bx : px_bx;
    const float* Wo = is_zt ? zt_Wo : px_Wo;
    const float* bo = is_zt ? zt_bo : px_bo;
    const float* coord = is_zt ? t : x;
    const float  mult  = is_zt ? zt_mult[0] : px_mult[0];
    const float* g = ws + (is_zt ? 512 : 0) + b * 128;
    float* outp = is_zt ? out_zt : out_px;

    __shared__ float f[8][128];
    {
        const float gv = g[tid];
        const float wxj = Wx[tid], bxj = bx[tid];
        #pragma unroll
        for (int rr = 0; rr < 8; ++rr)
            f[rr][tid] = __sinf(coord[r0 + rr] * wxj + bxj) * gv;
    }
    __syncthreads();

    const int c0 = cs * 512 + tid * 4;
    const float* wp = Wo + c0;          // row k at wp[k*1024]

    const float4 bias = *(const float4*)&bo[c0];
    float4 acc[8];
    #pragma unroll
    for (int rr = 0; rr < 8; ++rr) acc[rr] = bias;

    float4 wA[8], wB[8];
    #pragma unroll
    for (int i = 0; i < 8; ++i)
        wA[i] = *(const float4*)&wp[i * 1024];

    for (int gi = 0; gi < 8; ++gi) {
        const int k0 = gi * 16;         // wA holds rows k0..k0+7
        // load odd half (k0+8..k0+15) while consuming wA
        #pragma unroll
        for (int i = 0; i < 8; ++i)
            wB[i] = *(const float4*)&wp[(k0 + 8 + i) * 1024];
        #pragma unroll
        for (int rr = 0; rr < 8; ++rr) {
            const float4 f0 = *(const float4*)&f[rr][k0];
            const float4 f1 = *(const float4*)&f[rr][k0 + 4];
            fma4(acc[rr], f0.x, wA[0]); fma4(acc[rr], f0.y, wA[1]);
            fma4(acc[rr], f0.z, wA[2]); fma4(acc[rr], f0.w, wA[3]);
            fma4(acc[rr], f1.x, wA[4]); fma4(acc[rr], f1.y, wA[5]);
            fma4(acc[rr], f1.z, wA[6]); fma4(acc[rr], f1.w, wA[7]);
        }
        // load next even half (k0+16..k0+23) while consuming wB
        if (gi < 7) {
            #pragma unroll
            for (int i = 0; i < 8; ++i)
                wA[i] = *(const float4*)&wp[(k0 + 16 + i) * 1024];
        }
        #pragma unroll
        for (int rr = 0; rr < 8; ++rr) {
            const float4 f0 = *(const float4*)&f[rr][k0 + 8];
            const float4 f1 = *(const float4*)&f[rr][k0 + 12];
            fma4(acc[rr], f0.x, wB[0]); fma4(acc[rr], f0.y, wB[1]);
            fma4(acc[rr], f0.z, wB[2]); fma4(acc[rr], f0.w, wB[3]);
            fma4(acc[rr], f1.x, wB[4]); fma4(acc[rr], f1.y, wB[5]);
            fma4(acc[rr], f1.z, wB[6]); fma4(acc[rr], f1.w, wB[7]);
        }
    }

    #pragma unroll
    for (int rr = 0; rr < 8; ++rr) {
        float4 v;
        v.x = mult * acc[rr].x; v.y = mult * acc[rr].y;
        v.z = mult * acc[rr].z; v.w = mult * acc[rr].w;
        *(float4*)&outp[(r0 + rr) * 1024 + c0] = v;
    }
}

// u: 256 blocks = 4b x 16 t-tiles(16 rows) x 4 x-quarters(32). 256 thr.
// Thread (tx=tid&31, ty=tid>>5): outputs (t0+ty, x0+tx), (t0+ty+8, x0+tx).
// px chunk staged in LDS (pre-scaled by wc); zt rows read from global into
// registers (lane-duplicated -> single transaction), 16 loads in flight.
__global__ __launch_bounds__(256) void u_kernel(
    const float* __restrict__ zt, const float* __restrict__ px,
    const float* __restrict__ ws, float* __restrict__ out_u)
{
    const int tid = threadIdx.x;
    const int blk = blockIdx.x;
    const int b   = blk >> 6;
    const int rem = blk & 63;
    const int t0  = (rem >> 2) * 16;
    const int x0  = (rem & 3) * 32;

    __shared__ float4 pxs4[32][65];   // 32 rows x 64 f4, +1 f4 pad
    __shared__ float wcs[32];

    if (tid < 32) wcs[tid] = ws[1024 + tid];
    const float K0 = ws[1056];

    const int tx = tid & 31;
    const int ty = tid >> 5;          // 0..7

    const float* ztb = zt + (b * 256 + t0) * 1024;
    const float* pxb = px + (b * 128 + x0) * 1024;

    __syncthreads();                  // wcs visible

    float acc0 = 0.f, acc1 = 0.f;

    for (int chunk = 0; chunk < 4; ++chunk) {
        const int kc = chunk * 256;
        if (chunk) __syncthreads();   // previous reads done before overwrite
        // stage px chunk: 32 rows x 64 f4, scaled by wc
        #pragma unroll
        for (int i = 0; i < 8; ++i) {
            const int m  = tid + 256 * i;
            const int xx = m >> 6;            // 0..31
            const int jf = m & 63;            // f4 within chunk
            float4 v = *(const float4*)&pxb[xx * 1024 + kc + jf * 4];
            const float s = wcs[(kc >> 5) + (jf >> 3)];
            v.x *= s; v.y *= s; v.z *= s; v.w *= s;
            pxs4[xx][jf] = v;
        }
        __syncthreads();

        for (int jj = 0; jj < 8; ++jj) {
            float4 za[8], zb[8];
            const int koff = kc + jj * 32;
            #pragma unroll
            for (int j2 = 0; j2 < 8; ++j2) {
                za[j2] = *(const float4*)&ztb[ty * 1024 + koff + j2 * 4];
                zb[j2] = *(const float4*)&ztb[(ty + 8) * 1024 + koff + j2 * 4];
            }
            #pragma unroll
            for (int j2 = 0; j2 < 8; ++j2) {
                const float4 p = pxs4[tx][jj * 8 + j2];
                acc0 += za[j2].x * p.x + za[j2].y * p.y
                      + za[j2].z * p.z + za[j2].w * p.w;
                acc1 += zb[j2].x * p.x + zb[j2].y * p.y
                      + zb[j2].z * p.z + zb[j2].w * p.w;
            }
        }
    }

    out_u[(b * 256 + t0 + ty)     * 128 + x0 + tx] = K0 + acc0;
    out_u[(b * 256 + t0 + ty + 8) * 128 + x0 + tx] = K0 + acc1;
}

extern "C" void kernel_launch(void* const* d_in, const int* in_sizes, int n_in,
                              void* d_out, int out_size, void* d_ws, size_t ws_size,
                              hipStream_t stream) {
    const float* x       = (const float*)d_in[0];
    const float* t       = (const float*)d_in[1];
    const float* param   = (const float*)d_in[2];
    const float* p2e_W1  = (const float*)d_in[3];
    const float* p2e_b1  = (const float*)d_in[4];
    const float* p2e_W2  = (const float*)d_in[5];
    const float* p2e_b2  = (const float*)d_in[6];
    const float* e2ex_W  = (const float*)d_in[7];
    const float* e2ex_b  = (const float*)d_in[8];
    const float* e2et_W  = (const float*)d_in[9];
    const float* e2et_b  = (const float*)d_in[10];
    const float* px_Wx   = (const float*)d_in[11];
    const float* px_bx   = (const float*)d_in[12];
    const float* px_We   = (const float*)d_in[13];
    const float* px_be   = (const float*)d_in[14];
    const float* px_Wo   = (const float*)d_in[15];
    const float* px_bo   = (const float*)d_in[16];
    const float* px_mult = (const float*)d_in[17];
    const float* zt_Wx   = (const float*)d_in[18];
    const float* zt_bx   = (const float*)d_in[19];
    const float* zt_We   = (const float*)d_in[20];
    const float* zt_be   = (const float*)d_in[21];
    const float* zt_Wo   = (const float*)d_in[22];
    const float* zt_bo   = (const float*)d_in[23];
    const float* zt_mult = (const float*)d_in[24];
    const float* h0      = (const float*)d_in[25];
    const float* blk_W1  = (const float*)d_in[26];
    const float* blk_b1  = (const float*)d_in[27];
    const float* blk_Wc  = (const float*)d_in[28];
    const float* blk_bc  = (const float*)d_in[29];
    const float* blk_W2  = (const float*)d_in[30];
    const float* blk_b2  = (const float*)d_in[31];
    const float* d_W     = (const float*)d_in[32];
    const float* d_bias  = (const float*)d_in[33];

    float* out    = (float*)d_out;
    float* out_u  = out;                       // 131072
    float* out_zt = out + 131072;              // 1048576
    float* out_px = out + 131072 + 1048576;    // 524288

    float* ws = (float*)d_ws;

    prep_kernel<<<5, 128, 0, stream>>>(
        param, p2e_W1, p2e_b1, p2e_W2, p2e_b2,
        e2ex_W, e2ex_b, e2et_W, e2et_b,
        px_We, px_be, zt_We, zt_be,
        h0, blk_W1, blk_b1, blk_Wc, blk_bc, blk_W2, blk_b2,
        d_W, d_bias, ws);

    feat_kernel<<<384, 128, 0, stream>>>(
        x, t,
        px_Wx, px_bx, px_Wo, px_bo, px_mult,
        zt_Wx, zt_bx, zt_Wo, zt_bo, zt_mult,
        ws, out_px, out_zt);

    u_kernel<<<256, 256, 0, stream>>>(out_zt, out_px, ws, out_u);
}

// Round 7
// 49.105 us; speedup vs baseline: 1.3907x; 1.1387x over previous
//
#include <hip/hip_runtime.h>
#include <math.h>

// B=4, X=128, T=256, HIDDEN=128, EMB=128, DH=32, LATENT=32, K=1024
// Outputs concat: u (131072), zt (1048576), px (524288)
//
// u[b,t,x] = K0 + sum_k zt[b,t,k] * px[b,x,k] * wc[k>>5]   (wc = wcd/32)
//
// ws layout (floats):
//   [0..511]     gx[b][j] = ex @ px_We + px_be
//   [512..1023]  gt[b][j] = et @ zt_We + zt_be
//   [1024..1055] wc[d] = wcd[d]/32
//   [1056]       K0
//   [2048..]     u partials: 2 x 131072 (k-halves)

// prep: 5 blocks x 1024 thr. Slice-reduce each GEMV stage 8-way over k.
__global__ __launch_bounds__(1024) void prep_kernel(
    const float* __restrict__ param,
    const float* __restrict__ p2e_W1, const float* __restrict__ p2e_b1,
    const float* __restrict__ p2e_W2, const float* __restrict__ p2e_b2,
    const float* __restrict__ e2ex_W, const float* __restrict__ e2ex_b,
    const float* __restrict__ e2et_W, const float* __restrict__ e2et_b,
    const float* __restrict__ px_We,  const float* __restrict__ px_be,
    const float* __restrict__ zt_We,  const float* __restrict__ zt_be,
    const float* __restrict__ h0,
    const float* __restrict__ blk_W1, const float* __restrict__ blk_b1,
    const float* __restrict__ blk_Wc, const float* __restrict__ blk_bc,
    const float* __restrict__ blk_W2, const float* __restrict__ blk_b2,
    const float* __restrict__ d_W,    const float* __restrict__ d_b,
    float* __restrict__ ws)
{
    const int tid = threadIdx.x;
    const int j  = tid & 127;
    const int s  = tid >> 7;       // 0..7
    const int kb = s * 16;

    __shared__ float vinA[128], vinB[128];
    __shared__ float part[8][128], partB[8][128];
    __shared__ float wpart[32][8];

    if (blockIdx.x < 4) {
        const int b = blockIdx.x;
        if (s == 0) {
            float a = p2e_b1[j];
            #pragma unroll
            for (int p = 0; p < 16; ++p) a += param[b * 16 + p] * p2e_W1[p * 128 + j];
            vinA[j] = __sinf(a);
        }
        __syncthreads();
        // e = sin-layer @ p2e_W2 + b2
        {
            float p = 0.f;
            #pragma unroll
            for (int i = 0; i < 16; ++i) p += vinA[kb + i] * p2e_W2[(kb + i) * 128 + j];
            part[s][j] = p;
        }
        __syncthreads();
        if (s == 0) {
            float e = p2e_b2[j];
            #pragma unroll
            for (int q = 0; q < 8; ++q) e += part[q][j];
            vinB[j] = e;
        }
        __syncthreads();
        // ax, at
        {
            float pa = 0.f, pt = 0.f;
            #pragma unroll
            for (int i = 0; i < 16; ++i) {
                const float ek = vinB[kb + i];
                pa += ek * e2ex_W[(kb + i) * 128 + j];
                pt += ek * e2et_W[(kb + i) * 128 + j];
            }
            part[s][j] = pa; partB[s][j] = pt;
        }
        __syncthreads();
        if (s == 0) {
            float ax = e2ex_b[j], at = e2et_b[j];
            #pragma unroll
            for (int q = 0; q < 8; ++q) { ax += part[q][j]; at += partB[q][j]; }
            vinA[j] = ax; vinB[j] = at;
        }
        __syncthreads();
        // gx, gt
        {
            float pa = 0.f, pt = 0.f;
            #pragma unroll
            for (int i = 0; i < 16; ++i) {
                pa += vinA[kb + i] * px_We[(kb + i) * 128 + j];
                pt += vinB[kb + i] * zt_We[(kb + i) * 128 + j];
            }
            part[s][j] = pa; partB[s][j] = pt;
        }
        __syncthreads();
        if (s == 0) {
            float gx = px_be[j], gt = zt_be[j];
            #pragma unroll
            for (int q = 0; q < 8; ++q) { gx += part[q][j]; gt += partB[q][j]; }
            ws[b * 128 + j]       = gx;
            ws[512 + b * 128 + j] = gt;
        }
    } else {
        // constants: sacc (slice-reduced), w2d (row-per-thread), wcd, K0
        {
            float p = 0.f;
            #pragma unroll
            for (int i = 0; i < 16; ++i) p += h0[kb + i] * blk_W1[(kb + i) * 128 + j];
            part[s][j] = p;
        }
        {
            float p = 0.f;
            #pragma unroll
            for (int i = 0; i < 16; ++i) p += blk_W2[j * 128 + kb + i] * d_W[kb + i];
            partB[s][j] = p;
        }
        __syncthreads();
        if (s == 0) {
            float sa = blk_b1[j], w2 = 0.f;
            #pragma unroll
            for (int q = 0; q < 8; ++q) { sa += part[q][j]; w2 += partB[q][j]; }
            const float sw = __sinf(sa) * w2;
            vinA[j] = sw;                                        // sw vector
            vinB[j] = (h0[j] + blk_b2[j]) * d_W[j] + sw * blk_bc[j];  // K0 terms
        }
        __syncthreads();
        if (tid < 256) {
            const int d  = tid >> 3;
            const int s3 = (tid & 7) * 16;
            float p = 0.f;
            #pragma unroll
            for (int i = 0; i < 16; ++i) p += blk_Wc[d * 128 + s3 + i] * vinA[s3 + i];
            wpart[d][tid & 7] = p;
        }
        __syncthreads();
        if (tid < 32) {
            float w = 0.f;
            #pragma unroll
            for (int q = 0; q < 8; ++q) w += wpart[tid][q];
            ws[1024 + tid] = w * (1.0f / 32.0f);
        }
        // K0 reduce (wave 0 only below 64 -> lockstep, no barriers needed)
        if (tid < 64) part[0][tid] = vinB[tid] + vinB[tid + 64];
        __syncthreads();
        if (tid < 32) part[0][tid] += part[0][tid + 32];
        if (tid < 16) part[0][tid] += part[0][tid + 16];
        if (tid < 8)  part[0][tid] += part[0][tid + 8];
        if (tid < 4)  part[0][tid] += part[0][tid + 4];
        if (tid < 2)  part[0][tid] += part[0][tid + 2];
        if (tid == 0) ws[1056] = part[0][0] + part[0][1] + d_b[0];
    }
}

__device__ __forceinline__ void fma4(float4& a, float s, const float4& v) {
    a.x += s * v.x; a.y += s * v.y; a.z += s * v.z; a.w += s * v.w;
}

// feat: 384 blocks x 128 thr (unchanged from round 6).
__global__ __launch_bounds__(128, 1) void feat_kernel(
    const float* __restrict__ x, const float* __restrict__ t,
    const float* __restrict__ px_Wx, const float* __restrict__ px_bx,
    const float* __restrict__ px_Wo, const float* __restrict__ px_bo,
    const float* __restrict__ px_mult,
    const float* __restrict__ zt_Wx, const float* __restrict__ zt_bx,
    const float* __restrict__ zt_Wo, const float* __restrict__ zt_bo,
    const float* __restrict__ zt_mult,
    const float* __restrict__ ws,
    float* __restrict__ out_px, float* __restrict__ out_zt)
{
    const int tid = threadIdx.x;
    const bool is_zt = (blockIdx.x >= 128);
    const int idx = is_zt ? ((int)blockIdx.x - 128) : (int)blockIdx.x;
    const int rt = idx >> 1;
    const int cs = idx & 1;
    const int r0 = rt * 8;
    const int b  = is_zt ? (r0 >> 8) : (r0 >> 7);

    const float* Wx = is_zt ? zt_Wx : px_Wx;
    const float* bx = is_zt ? zt_bx : px_bx;
    const float* Wo = is_zt ? zt_Wo : px_Wo;
    const float* bo = is_zt ? zt_bo : px_bo;
    const float* coord = is_zt ? t : x;
    const float  mult  = is_zt ? zt_mult[0] : px_mult[0];
    const float* g = ws + (is_zt ? 512 : 0) + b * 128;
    float* outp = is_zt ? out_zt : out_px;

    __shared__ float f[8][128];
    {
        const float gv = g[tid];
        const float wxj = Wx[tid], bxj = bx[tid];
        #pragma unroll
        for (int rr = 0; rr < 8; ++rr)
            f[rr][tid] = __sinf(coord[r0 + rr] * wxj + bxj) * gv;
    }
    __syncthreads();

    const int c0 = cs * 512 + tid * 4;
    const float* wp = Wo + c0;

    const float4 bias = *(const float4*)&bo[c0];
    float4 acc[8];
    #pragma unroll
    for (int rr = 0; rr < 8; ++rr) acc[rr] = bias;

    float4 wA[8], wB[8];
    #pragma unroll
    for (int i = 0; i < 8; ++i)
        wA[i] = *(const float4*)&wp[i * 1024];

    for (int gi = 0; gi < 8; ++gi) {
        const int k0 = gi * 16;
        #pragma unroll
        for (int i = 0; i < 8; ++i)
            wB[i] = *(const float4*)&wp[(k0 + 8 + i) * 1024];
        #pragma unroll
        for (int rr = 0; rr < 8; ++rr) {
            const float4 f0 = *(const float4*)&f[rr][k0];
            const float4 f1 = *(const float4*)&f[rr][k0 + 4];
            fma4(acc[rr], f0.x, wA[0]); fma4(acc[rr], f0.y, wA[1]);
            fma4(acc[rr], f0.z, wA[2]); fma4(acc[rr], f0.w, wA[3]);
            fma4(acc[rr], f1.x, wA[4]); fma4(acc[rr], f1.y, wA[5]);
            fma4(acc[rr], f1.z, wA[6]); fma4(acc[rr], f1.w, wA[7]);
        }
        if (gi < 7) {
            #pragma unroll
            for (int i = 0; i < 8; ++i)
                wA[i] = *(const float4*)&wp[(k0 + 16 + i) * 1024];
        }
        #pragma unroll
        for (int rr = 0; rr < 8; ++rr) {
            const float4 f0 = *(const float4*)&f[rr][k0 + 8];
            const float4 f1 = *(const float4*)&f[rr][k0 + 12];
            fma4(acc[rr], f0.x, wB[0]); fma4(acc[rr], f0.y, wB[1]);
            fma4(acc[rr], f0.z, wB[2]); fma4(acc[rr], f0.w, wB[3]);
            fma4(acc[rr], f1.x, wB[4]); fma4(acc[rr], f1.y, wB[5]);
            fma4(acc[rr], f1.z, wB[6]); fma4(acc[rr], f1.w, wB[7]);
        }
    }

    #pragma unroll
    for (int rr = 0; rr < 8; ++rr) {
        float4 v;
        v.x = mult * acc[rr].x; v.y = mult * acc[rr].y;
        v.z = mult * acc[rr].z; v.w = mult * acc[rr].w;
        *(float4*)&outp[(r0 + rr) * 1024 + c0] = v;
    }
}

// u_partial: 512 blocks = 4b x 16 t-tiles x 4 x-quarters x 2 k-halves. 256 thr.
// Deterministic partials into ws+2048 (+kh*131072). jj-level register dbuf.
__global__ __launch_bounds__(256, 2) void u_partial_kernel(
    const float* __restrict__ zt, const float* __restrict__ px,
    const float* __restrict__ ws, float* __restrict__ pout)
{
    const int tid = threadIdx.x;
    const int blk = blockIdx.x;
    const int b   = blk >> 7;
    const int rem = blk & 127;
    const int t0  = (rem >> 3) * 16;
    const int x0  = ((rem >> 1) & 3) * 32;
    const int kh  = rem & 1;

    __shared__ float4 pxs4[32][65];
    __shared__ float wcs[32];
    if (tid < 32) wcs[tid] = ws[1024 + tid];

    const int tx = tid & 31;
    const int ty = tid >> 5;

    const float* ztb = zt + (b * 256 + t0) * 1024;
    const float* pxb = px + (b * 128 + x0) * 1024;
    __syncthreads();

    float acc0 = 0.f, acc1 = 0.f;

    for (int c = 0; c < 2; ++c) {
        const int kc = kh * 512 + c * 256;
        if (c) __syncthreads();
        #pragma unroll
        for (int i = 0; i < 8; ++i) {
            const int m  = tid + 256 * i;
            const int xx = m >> 6;
            const int jf = m & 63;
            float4 v = *(const float4*)&pxb[xx * 1024 + kc + jf * 4];
            const float sc = wcs[(kc >> 5) + (jf >> 3)];
            v.x *= sc; v.y *= sc; v.z *= sc; v.w *= sc;
            pxs4[xx][jf] = v;
        }
        __syncthreads();

        float4 za[8], zb[8];
        #pragma unroll
        for (int j2 = 0; j2 < 8; ++j2) {
            za[j2] = *(const float4*)&ztb[ty * 1024 + kc + j2 * 4];
            zb[j2] = *(const float4*)&ztb[(ty + 8) * 1024 + kc + j2 * 4];
        }
        #pragma unroll
        for (int jj = 0; jj < 8; ++jj) {
            float4 nza[8], nzb[8];
            if (jj < 7) {
                const int koff = kc + (jj + 1) * 32;
                #pragma unroll
                for (int j2 = 0; j2 < 8; ++j2) {
                    nza[j2] = *(const float4*)&ztb[ty * 1024 + koff + j2 * 4];
                    nzb[j2] = *(const float4*)&ztb[(ty + 8) * 1024 + koff + j2 * 4];
                }
            }
            #pragma unroll
            for (int j2 = 0; j2 < 8; ++j2) {
                const float4 p = pxs4[tx][jj * 8 + j2];
                acc0 += za[j2].x * p.x + za[j2].y * p.y
                      + za[j2].z * p.z + za[j2].w * p.w;
                acc1 += zb[j2].x * p.x + zb[j2].y * p.y
                      + zb[j2].z * p.z + zb[j2].w * p.w;
            }
            if (jj < 7) {
                #pragma unroll
                for (int j2 = 0; j2 < 8; ++j2) { za[j2] = nza[j2]; zb[j2] = nzb[j2]; }
            }
        }
    }

    float* po = pout + kh * 131072;
    po[(b * 256 + t0 + ty)     * 128 + x0 + tx] = acc0;
    po[(b * 256 + t0 + ty + 8) * 128 + x0 + tx] = acc1;
}

// u_reduce: out_u = K0 + partial0 + partial1. 128 blocks x 256 thr x float4.
__global__ __launch_bounds__(256) void u_reduce_kernel(
    const float* __restrict__ ws, float* __restrict__ out_u)
{
    const int i = ((int)blockIdx.x * 256 + (int)threadIdx.x) * 4;
    const float K0 = ws[1056];
    const float4 a = *(const float4*)&ws[2048 + i];
    const float4 c = *(const float4*)&ws[2048 + 131072 + i];
    float4 v;
    v.x = K0 + a.x + c.x; v.y = K0 + a.y + c.y;
    v.z = K0 + a.z + c.z; v.w = K0 + a.w + c.w;
    *(float4*)&out_u[i] = v;
}

extern "C" void kernel_launch(void* const* d_in, const int* in_sizes, int n_in,
                              void* d_out, int out_size, void* d_ws, size_t ws_size,
                              hipStream_t stream) {
    const float* x       = (const float*)d_in[0];
    const float* t       = (const float*)d_in[1];
    const float* param   = (const float*)d_in[2];
    const float* p2e_W1  = (const float*)d_in[3];
    const float* p2e_b1  = (const float*)d_in[4];
    const float* p2e_W2  = (const float*)d_in[5];
    const float* p2e_b2  = (const float*)d_in[6];
    const float* e2ex_W  = (const float*)d_in[7];
    const float* e2ex_b  = (const float*)d_in[8];
    const float* e2et_W  = (const float*)d_in[9];
    const float* e2et_b  = (const float*)d_in[10];
    const float* px_Wx   = (const float*)d_in[11];
    const float* px_bx   = (const float*)d_in[12];
    const float* px_We   = (const float*)d_in[13];
    const float* px_be   = (const float*)d_in[14];
    const float* px_Wo   = (const float*)d_in[15];
    const float* px_bo   = (const float*)d_in[16];
    const float* px_mult = (const float*)d_in[17];
    const float* zt_Wx   = (const float*)d_in[18];
    const float* zt_bx   = (const float*)d_in[19];
    const float* zt_We   = (const float*)d_in[20];
    const float* zt_be   = (const float*)d_in[21];
    const float* zt_Wo   = (const float*)d_in[22];
    const float* zt_bo   = (const float*)d_in[23];
    const float* zt_mult = (const float*)d_in[24];
    const float* h0      = (const float*)d_in[25];
    const float* blk_W1  = (const float*)d_in[26];
    const float* blk_b1  = (const float*)d_in[27];
    const float* blk_Wc  = (const float*)d_in[28];
    const float* blk_bc  = (const float*)d_in[29];
    const float* blk_W2  = (const float*)d_in[30];
    const float* blk_b2  = (const float*)d_in[31];
    const float* d_W     = (const float*)d_in[32];
    const float* d_bias  = (const float*)d_in[33];

    float* out    = (float*)d_out;
    float* out_u  = out;                       // 131072
    float* out_zt = out + 131072;              // 1048576
    float* out_px = out + 131072 + 1048576;    // 524288

    float* ws = (float*)d_ws;

    prep_kernel<<<5, 1024, 0, stream>>>(
        param, p2e_W1, p2e_b1, p2e_W2, p2e_b2,
        e2ex_W, e2ex_b, e2et_W, e2et_b,
        px_We, px_be, zt_We, zt_be,
        h0, blk_W1, blk_b1, blk_Wc, blk_bc, blk_W2, blk_b2,
        d_W, d_bias, ws);

    feat_kernel<<<384, 128, 0, stream>>>(
        x, t,
        px_Wx, px_bx, px_Wo, px_bo, px_mult,
        zt_Wx, zt_bx, zt_Wo, zt_bo, zt_mult,
        ws, out_px, out_zt);

    u_partial_kernel<<<512, 256, 0, stream>>>(out_zt, out_px, ws, ws + 2048);

    u_reduce_kernel<<<128, 256, 0, stream>>>(ws, out_u);
}